// Round 3
// baseline (4315.002 us; speedup 1.0000x reference)
//
#include <hip/hip_runtime.h>
#include <hip/hip_bf16.h>
#include <math.h>

typedef __bf16 bf16_t;
typedef __bf16 bf16x8 __attribute__((ext_vector_type(8)));
typedef float f32x4 __attribute__((ext_vector_type(4)));
typedef unsigned short ushort_t;

#define NB   40
#define NT   20
#define FEA  200
#define HD   1024
#define NOUT 1095
#define NL   12
#define M_ROWS (NB*NT)   // 800
#define UPITCH 196       // fp32 pitch for U in LDS

// ---- dual-dtype helpers: f32 flag selects fp32 vs bf16 external buffers ----
__device__ __forceinline__ float ldx(const void* p, size_t i, bool f32) {
    return f32 ? ((const float*)p)[i] : (float)((const bf16_t*)p)[i];
}
__device__ __forceinline__ ushort_t ldbits(const void* p, size_t i, bool f32) {
    if (f32) { bf16_t t = (bf16_t)((const float*)p)[i]; return *(const ushort_t*)&t; }
    return ((const ushort_t*)p)[i];
}
__device__ __forceinline__ void stx(void* p, size_t i, float v, bool f32) {
    if (f32) ((float*)p)[i] = v;
    else     ((bf16_t*)p)[i] = (bf16_t)v;
}

// ---------------------------------------------------------------------------
// Probe: decide whether inputs are fp32 or bf16 by bit-pattern statistics.
// x ~ N(0,1). As bf16 pairs, u16[2i] is a real sample -> exponent in [110,135]
// ~always. As fp32, u16[2i] is low mantissa bits -> uniform exponent, ~10% hit.
// ---------------------------------------------------------------------------
__global__ void probe_kernel(const void* __restrict__ x, int* __restrict__ flag)
{
    if (threadIdx.x == 0 && blockIdx.x == 0) {
        const ushort_t* u = (const ushort_t*)x;
        int cnt = 0;
        for (int i = 0; i < 256; i++) {
            const int e = (u[2*i] >> 7) & 0xFF;
            if (e >= 110 && e <= 135) cnt++;
        }
        *flag = (cnt < 128) ? 1 : 0;   // 1 => fp32 inputs/outputs
    }
}

// ---------------------------------------------------------------------------
// GEMM: C[M,N] = A[M,K] @ B[K,N] (+bias)(+relu). 64x64 tile, BK=32, 256 thr,
// MFMA 16x16x32 bf16 (verified layouts: A[m=l16][k=quad*8+j], B[n=l16][k=quad*8+j],
// D col=l16, row=quad*4+reg). A_EXT/C_EXT: buffer follows external dtype flag;
// internal buffers are always bf16.
// ---------------------------------------------------------------------------
template<bool A_EXT, bool C_EXT, bool BIAS, bool RELU>
__global__ __launch_bounds__(256)
void gemm_kernel(const void* __restrict__ A, const void* __restrict__ Bm,
                 const void* __restrict__ bias, void* __restrict__ C,
                 int M, int N, int K, const int* __restrict__ flag)
{
    const bool f32 = (*flag != 0);

    __shared__ __attribute__((aligned(16))) ushort_t As[64*40];
    __shared__ __attribute__((aligned(16))) ushort_t Bs[64*40];

    const int tid  = threadIdx.x;
    const int wave = tid >> 6;
    const int lane = tid & 63;
    const int quad = lane >> 4;
    const int l16  = lane & 15;

    const int m0 = blockIdx.y * 64;
    const int n0 = blockIdx.x * 64;

    f32x4 acc[4];
    #pragma unroll
    for (int i = 0; i < 4; i++) acc[i] = (f32x4){0.f, 0.f, 0.f, 0.f};

    const int ar = tid >> 2;         // 0..63
    const int ac = (tid & 3) << 3;   // 0,8,16,24
    const int bk = tid >> 3;         // 0..31
    const int bn = (tid & 7) << 3;   // 0..56

    for (int k0 = 0; k0 < K; k0 += 32) {
        ushort_t ta[8], tb[8];
        {   // ---- A tile [64 x 32] ----
            const int gm = m0 + ar, gk = k0 + ac;
            if (A_EXT && f32) {
                #pragma unroll
                for (int j = 0; j < 8; j++)
                    ta[j] = (gm < M && gk + j < K)
                          ? ldbits(A, (size_t)gm * K + gk + j, true) : (ushort_t)0;
            } else {
                const ushort_t* Ag = (const ushort_t*)A;
                if (gm < M && gk + 7 < K) {
                    *(uint4*)ta = *(const uint4*)&Ag[(size_t)gm * K + gk];
                } else {
                    #pragma unroll
                    for (int j = 0; j < 8; j++)
                        ta[j] = (gm < M && gk + j < K) ? Ag[(size_t)gm * K + gk + j] : (ushort_t)0;
                }
            }
        }
        {   // ---- B tile [32 x 64] (B always external) ----
            const int gk = k0 + bk, gn = n0 + bn;
            if (!f32 && ((N & 7) == 0) && gk < K && gn + 7 < N) {
                const ushort_t* Bg = (const ushort_t*)Bm;
                *(uint4*)tb = *(const uint4*)&Bg[(size_t)gk * N + gn];
            } else {
                #pragma unroll
                for (int j = 0; j < 8; j++)
                    tb[j] = (gk < K && gn + j < N)
                          ? ldbits(Bm, (size_t)gk * N + gn + j, f32) : (ushort_t)0;
            }
        }
        __syncthreads();   // previous iter's fragment reads complete
        *(uint4*)&As[ar*40 + ac] = *(const uint4*)ta;
        #pragma unroll
        for (int j = 0; j < 8; j++) Bs[(bn + j)*40 + bk] = tb[j];
        __syncthreads();

        bf16x8 a = *(const bf16x8*)&As[(wave*16 + l16)*40 + quad*8];
        #pragma unroll
        for (int nt = 0; nt < 4; nt++) {
            bf16x8 b = *(const bf16x8*)&Bs[(nt*16 + l16)*40 + quad*8];
            acc[nt] = __builtin_amdgcn_mfma_f32_16x16x32_bf16(a, b, acc[nt], 0, 0, 0);
        }
    }

    #pragma unroll
    for (int nt = 0; nt < 4; nt++) {
        const int n = n0 + nt*16 + l16;
        float bv = 0.f;
        if (BIAS && n < N) bv = ldx(bias, (size_t)n, f32);
        #pragma unroll
        for (int i = 0; i < 4; i++) {
            const int m = m0 + wave*16 + quad*4 + i;
            if (m < M && n < N) {
                float v = acc[nt][i] + bv;
                if (RELU) v = v > 0.f ? v : 0.f;
                if (C_EXT) stx(C, (size_t)m * N + n, v, f32);
                else       ((bf16_t*)C)[(size_t)m * N + n] = (bf16_t)v;
            }
        }
    }
}

// ---------------------------------------------------------------------------
// Fused SRU layer: block = 4 batches x 64 h-cols. GEMM U = h_in @ W[:,cols]
// (M=80, N=192, K=1024) with U in LDS (fp32), then 20-step recurrence.
// h buffers are internal bf16; W / c0 / b / cout are external (flag dtype).
// ---------------------------------------------------------------------------
__global__ __launch_bounds__(256)
void sru_layer_kernel(const bf16_t* __restrict__ hin, bf16_t* __restrict__ hout,
                      const void* __restrict__ Wall,   // [L,1024,3072]
                      const void* __restrict__ c0all,  // [L,40,1024]
                      const void* __restrict__ ball,   // [L,2048]
                      void* __restrict__ outAll,       // d_out (flag dtype)
                      int layer, const int* __restrict__ flag)
{
    const bool f32 = (*flag != 0);

    __shared__ __attribute__((aligned(16))) float smem_f[80 * UPITCH]; // 62720 B
    ushort_t* As = (ushort_t*)smem_f;                    // [80][40]
    ushort_t* Bs = (ushort_t*)((char*)smem_f + 80*40*2); // [192][40]
    float*    Ul = smem_f;                               // [80][UPITCH]

    const int tid  = threadIdx.x;
    const int wave = tid >> 6;
    const int lane = tid & 63;
    const int quad = lane >> 4;
    const int l16  = lane & 15;

    const int n0 = blockIdx.x * 64;   // 0..960
    const int bi = blockIdx.y;        // 0..9

    const ushort_t* hg = (const ushort_t*)hin;
    const size_t Woff = (size_t)layer * HD * 3 * HD;

    f32x4 acc[5][3];
    #pragma unroll
    for (int rt = 0; rt < 5; rt++)
        #pragma unroll
        for (int ct = 0; ct < 3; ct++) acc[rt][ct] = (f32x4){0.f,0.f,0.f,0.f};

    const int arow  = tid >> 2;        // 0..63
    const int akoct = (tid & 3) << 3;  // 0,8,16,24
    const int arow2 = 64 + (tid >> 2); // rows 64..79 (tid<64)

    for (int k0 = 0; k0 < HD; k0 += 32) {
        // A: internal bf16, vectorized
        uint4 a0 = *(const uint4*)&hg[(size_t)(bi*80 + arow)*HD + k0 + akoct];
        uint4 a1;
        if (tid < 64)
            a1 = *(const uint4*)&hg[(size_t)(bi*80 + arow2)*HD + k0 + akoct];
        // B: external gather-transpose (scalar, dual dtype)
        ushort_t bt[3][8];
        #pragma unroll
        for (int q = 0; q < 3; q++)
            #pragma unroll
            for (int j = 0; j < 8; j++)
                bt[q][j] = ldbits(Wall,
                    Woff + (size_t)(k0 + wave*8 + j)*(3*HD) + q*HD + n0 + lane, f32);

        __syncthreads();
        *(uint4*)&As[arow*40 + akoct] = a0;
        if (tid < 64) *(uint4*)&As[arow2*40 + akoct] = a1;
        #pragma unroll
        for (int q = 0; q < 3; q++)
            *(uint4*)&Bs[(q*64 + lane)*40 + wave*8] = *(const uint4*)bt[q];
        __syncthreads();

        bf16x8 af[5], bfr[3];
        #pragma unroll
        for (int rt = 0; rt < 5; rt++)
            af[rt] = *(const bf16x8*)&As[(rt*16 + l16)*40 + quad*8];
        #pragma unroll
        for (int ct = 0; ct < 3; ct++)
            bfr[ct] = *(const bf16x8*)&Bs[((wave*3 + ct)*16 + l16)*40 + quad*8];
        #pragma unroll
        for (int rt = 0; rt < 5; rt++)
            #pragma unroll
            for (int ct = 0; ct < 3; ct++)
                acc[rt][ct] = __builtin_amdgcn_mfma_f32_16x16x32_bf16(af[rt], bfr[ct], acc[rt][ct], 0, 0, 0);
    }

    __syncthreads();   // staging reads done before smem reused as Ul
    #pragma unroll
    for (int rt = 0; rt < 5; rt++)
        #pragma unroll
        for (int ct = 0; ct < 3; ct++) {
            const int col = (wave*3 + ct)*16 + l16;
            #pragma unroll
            for (int i = 0; i < 4; i++)
                Ul[(rt*16 + quad*4 + i)*UPITCH + col] = acc[rt][ct][i];
        }
    __syncthreads();

    // ---- recurrence: thread = (local batch, col) ----
    const int bl = tid >> 6;
    const int nn = tid & 63;
    const int bg = bi*4 + bl;
    float c = ldx(c0all, (size_t)layer*NB*HD + (size_t)bg*HD + n0 + nn, f32);
    const float bfb = ldx(ball, (size_t)layer*2*HD + n0 + nn, f32);
    const float brb = ldx(ball, (size_t)layer*2*HD + HD + n0 + nn, f32);

    for (int t = 0; t < NT; t++) {
        const float* u = &Ul[(bl*NT + t)*UPITCH];
        const float xt = u[nn];
        const float uf = u[64 + nn];
        const float ur = u[128 + nn];
        const float f = 1.f / (1.f + __expf(-(uf + bfb)));
        const float r = 1.f / (1.f + __expf(-(ur + brb)));
        c = f * c + (1.f - f) * xt;
        const size_t gi = (size_t)(bg*NT + t)*HD + n0 + nn;
        const float hp = (float)hin[gi];
        hout[gi] = (bf16_t)(r * tanhf(c) + (1.f - r) * hp);
    }
    stx(outAll, (size_t)M_ROWS*NOUT + (size_t)layer*NB*HD + (size_t)bg*HD + n0 + nn, c, f32);
}

// ---------------------------------------------------------------------------
extern "C" void kernel_launch(void* const* d_in, const int* in_sizes, int n_in,
                              void* d_out, int out_size, void* d_ws, size_t ws_size,
                              hipStream_t stream)
{
    const void* x      = d_in[0];
    const void* hidden = d_in[1];
    const void* W1     = d_in[2];
    const void* b1     = d_in[3];
    const void* sruW   = d_in[4];
    const void* srub   = d_in[5];
    const void* W3     = d_in[6];
    const void* b3     = d_in[7];
    const void* W4     = d_in[8];
    const void* b4     = d_in[9];

    // Internal h ping-pong (always bf16): h0 in d_out's out0 region (dead by
    // the final GEMM; bytes 0..1.64MB < out0 bytes in either dtype), h1 in ws.
    // ws use: 819200*2 B for h1 + 4 B flag = 1,638,404 B.
    bf16_t* h0 = (bf16_t*)d_out;
    bf16_t* h1 = (bf16_t*)d_ws;
    bf16_t* g  = h1;   // reuses h1 after layers (dead)
    int* flag  = (int*)((char*)d_ws + (size_t)M_ROWS * HD * 2);

    const dim3 blk(256);
    const int mty = (M_ROWS + 63) / 64;   // 13

    probe_kernel<<<1, 64, 0, stream>>>(x, flag);

    // dense1: h0 = x @ W1 + b1   [800,200]@[200,1024] -> bf16 internal
    gemm_kernel<true, false, true, false><<<dim3(HD/64, mty), blk, 0, stream>>>(
        x, W1, b1, h0, M_ROWS, HD, FEA, flag);

    for (int l = 0; l < NL; l++) {
        const bf16_t* hin = (l & 1) ? h1 : h0;
        bf16_t*       hot = (l & 1) ? h0 : h1;
        sru_layer_kernel<<<dim3(HD/64, NB/4), blk, 0, stream>>>(
            hin, hot, sruW, hidden, srub, d_out, l, flag);
    }
    // layer 11 read h1, wrote h0 -> final h in h0

    // g = relu(h0 @ W3 + b3)   internal -> internal
    gemm_kernel<false, false, true, true><<<dim3(HD/64, mty), blk, 0, stream>>>(
        h0, W3, b3, g, M_ROWS, HD, HD, flag);

    // out0 = g @ W4 + b4   internal A -> external C (overwrites h0 region)
    gemm_kernel<false, true, true, false><<<dim3((NOUT + 63)/64, mty), blk, 0, stream>>>(
        g, W4, b4, d_out, M_ROWS, NOUT, HD, flag);
}

// Round 4
// 808.074 us; speedup vs baseline: 5.3399x; 5.3399x over previous
//
#include <hip/hip_runtime.h>
#include <hip/hip_bf16.h>
#include <math.h>

typedef __bf16 bf16_t;
typedef __bf16 bf16x8 __attribute__((ext_vector_type(8)));
typedef float f32x4 __attribute__((ext_vector_type(4)));
typedef unsigned short u16;

#define NB   40
#define NT   20
#define FEA  200
#define HD   1024
#define NOUT 1095
#define NL   12
#define M_ROWS 800      // NB*NT
#define UPITCH 196      // fp32 pitch for U in LDS (192 + 4 pad)

// ---------------------------------------------------------------------------
// Transpose+convert: src fp32 logical [srcK][srcN] (row stride srcN) ->
// dst bf16 [Np][Kp] with dst[n][k] = (k<srcK && n<srcN) ? src[k][n] : 0.
// 64x64 tile per block via LDS (pitch 66 u16: odd-dword stride -> conflict-free).
// blockIdx.z = layer (src += z*srcK*srcN, dst += z*Np*Kp).
// ---------------------------------------------------------------------------
__global__ __launch_bounds__(256)
void transpose_convert(const float* __restrict__ src, bf16_t* __restrict__ dst,
                       int srcK, int srcN, int Kp, int Np)
{
    __shared__ u16 tile[64 * 66];
    const int t = threadIdx.x;
    src += (size_t)blockIdx.z * srcK * srcN;
    dst += (size_t)blockIdx.z * Np * Kp;
    const int n0 = blockIdx.x << 6, k0 = blockIdx.y << 6;

    // load: thread t -> col n0+(t&63) (coalesced across lanes), 16 rows
    {
        const int nl = t & 63, kb = (t >> 6) << 4;
        const int gn = n0 + nl;
        #pragma unroll
        for (int j = 0; j < 16; j++) {
            const int gk = k0 + kb + j;
            float v = (gk < srcK && gn < srcN) ? src[(size_t)gk * srcN + gn] : 0.f;
            bf16_t b = (bf16_t)v;
            tile[nl * 66 + kb + j] = *(const u16*)&b;
        }
    }
    __syncthreads();
    // store: thread t -> dst row n0+(t>>2), k chunk k0+(t&3)*16, 2x uint4
    {
        const int nl = t >> 2, kg = (t & 3) << 4;
        const unsigned* tp = (const unsigned*)tile;
        const int dw = nl * 33 + (kg >> 1);
        uint4 v0, v1;
        v0.x = tp[dw+0]; v0.y = tp[dw+1]; v0.z = tp[dw+2]; v0.w = tp[dw+3];
        v1.x = tp[dw+4]; v1.y = tp[dw+5]; v1.z = tp[dw+6]; v1.w = tp[dw+7];
        bf16_t* dp = dst + (size_t)(n0 + nl) * Kp + k0 + kg;
        *(uint4*)dp = v0;
        *(uint4*)(dp + 8) = v1;
    }
}

// x [800][200] fp32 -> xb [800][256] bf16, zero-padded K. grid 800 x 256thr.
__global__ __launch_bounds__(256)
void convert_pad_x(const float* __restrict__ src, bf16_t* __restrict__ dst)
{
    const int m = blockIdx.x, k = threadIdx.x;
    dst[m * 256 + k] = (bf16_t)((k < FEA) ? src[(size_t)m * FEA + k] : 0.f);
}

// ---------------------------------------------------------------------------
// Direct-fragment GEMM: C[M,Nstore] = A[M,Ks]bf16 @ Bt[n][k]bf16 (+bias fp32)
// (+relu). No LDS, no barriers: fragments load straight from global.
// Block 256 thr: wave w -> row-tile blockIdx.y*4+w (rows clamped to M-1),
// 4 col-tiles at n0=blockIdx.x*64. MFMA 16x16x32 bf16.
// Verified layouts: A[m=l16][k=quad*8+j], B[n=l16][k=quad*8+j],
// D col=l16, row=quad*4+reg.
// ---------------------------------------------------------------------------
template<bool OUT_F32, bool RELU>
__global__ __launch_bounds__(256)
void gemm_tn(const bf16_t* __restrict__ A, const bf16_t* __restrict__ Bt,
             const float* __restrict__ bias, void* __restrict__ C,
             int M, int Nstore, int Ks)
{
    const int tid = threadIdx.x;
    const int w = tid >> 6, lane = tid & 63, quad = lane >> 4, l16 = lane & 15;
    const int n0 = blockIdx.x << 6;
    const int r0 = (blockIdx.y * 4 + w) << 4;

    int arow = r0 + l16; if (arow > M - 1) arow = M - 1;
    const bf16_t* ap = A + (size_t)arow * Ks + quad * 8;
    const bf16_t* bp[4];
    #pragma unroll
    for (int ct = 0; ct < 4; ct++)
        bp[ct] = Bt + (size_t)(n0 + ct * 16 + l16) * Ks + quad * 8;

    f32x4 acc[4];
    #pragma unroll
    for (int i = 0; i < 4; i++) acc[i] = (f32x4){0.f, 0.f, 0.f, 0.f};

    #pragma unroll 2
    for (int k0 = 0; k0 < Ks; k0 += 32) {
        bf16x8 a = *(const bf16x8*)(ap + k0);
        #pragma unroll
        for (int ct = 0; ct < 4; ct++) {
            bf16x8 b = *(const bf16x8*)(bp[ct] + k0);
            acc[ct] = __builtin_amdgcn_mfma_f32_16x16x32_bf16(a, b, acc[ct], 0, 0, 0);
        }
    }

    #pragma unroll
    for (int ct = 0; ct < 4; ct++) {
        const int col = n0 + ct * 16 + l16;
        if (col >= Nstore) continue;
        const float bv = bias ? bias[col] : 0.f;
        #pragma unroll
        for (int i = 0; i < 4; i++) {
            const int m = r0 + quad * 4 + i;
            if (m < M) {
                float v = acc[ct][i] + bv;
                if (RELU) v = v > 0.f ? v : 0.f;
                if (OUT_F32) ((float*)C)[(size_t)m * Nstore + col] = v;
                else         ((bf16_t*)C)[(size_t)m * Nstore + col] = (bf16_t)v;
            }
        }
    }
}

// ---------------------------------------------------------------------------
// Fused SRU layer. Block = 4 batches (80 rows) x 64 h-cols. GEMM (M=80,
// N=192 [3 gates x 64], K=1024) with direct global fragments from h (bf16)
// and Wt (bf16 [3072][1024], n-major). U -> LDS fp32, one barrier, then the
// 20-step recurrence + highway. c_last -> d_out hidden section (fp32).
// ---------------------------------------------------------------------------
__global__ __launch_bounds__(256)
void sru_layer(const bf16_t* __restrict__ hin, bf16_t* __restrict__ hout,
               const bf16_t* __restrict__ Wt, const float* __restrict__ c0,
               const float* __restrict__ bvec, float* __restrict__ cout)
{
    __shared__ float Ul[80 * UPITCH];   // 62720 B

    const int tid = threadIdx.x;
    const int w = tid >> 6, lane = tid & 63, quad = lane >> 4, l16 = lane & 15;
    const int n0 = blockIdx.x << 6;    // 0..960
    const int bi = blockIdx.y;         // 0..9 (4 batches each)

    f32x4 acc[5][3];
    #pragma unroll
    for (int rt = 0; rt < 5; rt++)
        #pragma unroll
        for (int ct = 0; ct < 3; ct++) acc[rt][ct] = (f32x4){0.f, 0.f, 0.f, 0.f};

    // U col-tile ctt = w*3+ct covers U cols [ctt*16, +16); U col c maps to
    // gate g=c>>6, W row g*HD + n0 + (c&63).
    const bf16_t* bp[3];
    #pragma unroll
    for (int ct = 0; ct < 3; ct++) {
        const int ctt = w * 3 + ct;
        bp[ct] = Wt + (size_t)((ctt >> 2) * HD + n0 + ((ctt & 3) << 4) + l16) * HD + quad * 8;
    }
    const bf16_t* ap[5];
    #pragma unroll
    for (int rt = 0; rt < 5; rt++)
        ap[rt] = hin + (size_t)(bi * 80 + rt * 16 + l16) * HD + quad * 8;

    #pragma unroll 2
    for (int k0 = 0; k0 < HD; k0 += 32) {
        bf16x8 a[5], b[3];
        #pragma unroll
        for (int rt = 0; rt < 5; rt++) a[rt] = *(const bf16x8*)(ap[rt] + k0);
        #pragma unroll
        for (int ct = 0; ct < 3; ct++) b[ct] = *(const bf16x8*)(bp[ct] + k0);
        #pragma unroll
        for (int rt = 0; rt < 5; rt++)
            #pragma unroll
            for (int ct = 0; ct < 3; ct++)
                acc[rt][ct] = __builtin_amdgcn_mfma_f32_16x16x32_bf16(a[rt], b[ct], acc[rt][ct], 0, 0, 0);
    }

    #pragma unroll
    for (int rt = 0; rt < 5; rt++)
        #pragma unroll
        for (int ct = 0; ct < 3; ct++) {
            const int col = (w * 3 + ct) * 16 + l16;
            #pragma unroll
            for (int i = 0; i < 4; i++)
                Ul[(rt * 16 + quad * 4 + i) * UPITCH + col] = acc[rt][ct][i];
        }
    __syncthreads();

    // recurrence: thread = (local batch bl, col nn)
    const int bl = tid >> 6, nn = tid & 63, bg = bi * 4 + bl;
    float c = c0[(size_t)bg * HD + n0 + nn];
    const float bfb = bvec[n0 + nn], brb = bvec[HD + n0 + nn];

    for (int t = 0; t < NT; t++) {
        const float* u = &Ul[(bl * NT + t) * UPITCH];
        const float xt = u[nn];
        const float uf = u[64 + nn];
        const float ur = u[128 + nn];
        const float f = 1.f / (1.f + __expf(-(uf + bfb)));
        const float r = 1.f / (1.f + __expf(-(ur + brb)));
        c = f * c + (1.f - f) * xt;
        const size_t gi = (size_t)(bg * NT + t) * HD + n0 + nn;
        const float hp = (float)hin[gi];
        hout[gi] = (bf16_t)(r * tanhf(c) + (1.f - r) * hp);
    }
    cout[(size_t)bg * HD + n0 + nn] = c;
}

// ---------------------------------------------------------------------------
extern "C" void kernel_launch(void* const* d_in, const int* in_sizes, int n_in,
                              void* d_out, int out_size, void* d_ws, size_t ws_size,
                              hipStream_t stream)
{
    const float* x      = (const float*)d_in[0];
    const float* hidden = (const float*)d_in[1];
    const float* W1     = (const float*)d_in[2];
    const float* b1     = (const float*)d_in[3];
    const float* sruW   = (const float*)d_in[4];
    const float* srub   = (const float*)d_in[5];
    const float* W3     = (const float*)d_in[6];
    const float* b3     = (const float*)d_in[7];
    const float* W4     = (const float*)d_in[8];
    const float* b4     = (const float*)d_in[9];

    float* out     = (float*)d_out;
    float* hid_out = out + (size_t)M_ROWS * NOUT;          // [12,40,1024] fp32

    // h0 (bf16, 1.64 MB) lives in d_out's out0 region (3.50 MB fp32, dead
    // until the final GEMM fully overwrites it; final GEMM reads only g).
    bf16_t* h0 = (bf16_t*)d_out;

    char* ws = (char*)d_ws;
    const size_t SZ_WT  = (size_t)NL * 3 * HD * HD * 2;    // 75,497,472
    const size_t SZ_W1  = (size_t)HD * 256 * 2;            //    524,288
    const size_t SZ_W3  = (size_t)HD * HD * 2;             //  2,097,152
    const size_t SZ_W4  = (size_t)1152 * HD * 2;           //  2,359,296
    const size_t SZ_XB  = (size_t)M_ROWS * 256 * 2;        //    409,600
    const size_t SZ_H   = (size_t)M_ROWS * HD * 2;         //  1,638,400
    const size_t SLOT   = (size_t)3 * HD * HD * 2;         //  6,291,456
    const size_t FAST_NEED = SZ_WT + SZ_W1 + SZ_W3 + SZ_W4 + SZ_XB + 2 * SZ_H;
    const bool fast = ws_size >= FAST_NEED;

    const dim3 blk(256);

    if (fast) {
        bf16_t* wt  = (bf16_t*)ws;
        bf16_t* w1t = (bf16_t*)(ws + SZ_WT);
        bf16_t* w3t = (bf16_t*)(ws + SZ_WT + SZ_W1);
        bf16_t* w4t = (bf16_t*)(ws + SZ_WT + SZ_W1 + SZ_W3);
        bf16_t* xb  = (bf16_t*)(ws + SZ_WT + SZ_W1 + SZ_W3 + SZ_W4);
        bf16_t* h1  = (bf16_t*)(ws + SZ_WT + SZ_W1 + SZ_W3 + SZ_W4 + SZ_XB);
        bf16_t* g   = (bf16_t*)(ws + SZ_WT + SZ_W1 + SZ_W3 + SZ_W4 + SZ_XB + SZ_H);

        convert_pad_x<<<M_ROWS, blk, 0, stream>>>(x, xb);
        transpose_convert<<<dim3(16, 4, 1),  blk, 0, stream>>>(W1,   w1t, FEA, HD,    256, HD);
        transpose_convert<<<dim3(48, 16, NL), blk, 0, stream>>>(sruW, wt,  HD,  3*HD, HD,  3*HD);
        transpose_convert<<<dim3(16, 16, 1), blk, 0, stream>>>(W3,   w3t, HD,  HD,   HD,  HD);
        transpose_convert<<<dim3(18, 16, 1), blk, 0, stream>>>(W4,   w4t, HD,  NOUT, HD,  1152);

        gemm_tn<false, false><<<dim3(16, 13), blk, 0, stream>>>(xb, w1t, b1, h0, M_ROWS, HD, 256);

        for (int l = 0; l < NL; l++) {
            const bf16_t* hi = (l & 1) ? h1 : h0;
            bf16_t*       ho = (l & 1) ? h0 : h1;
            sru_layer<<<dim3(16, 10), blk, 0, stream>>>(
                hi, ho, wt + (size_t)l * 3 * HD * HD,
                hidden + (size_t)l * NB * HD, srub + (size_t)l * 2 * HD,
                hid_out + (size_t)l * NB * HD);
        }
        // final h in h0
        gemm_tn<false, true><<<dim3(16, 13), blk, 0, stream>>>(h0, w3t, b3, g, M_ROWS, HD, HD);
        gemm_tn<true, false><<<dim3(18, 13), blk, 0, stream>>>(g, w4t, b4, out, M_ROWS, NOUT, HD);
    } else {
        bf16_t* slot = (bf16_t*)ws;                        // reused per weight
        bf16_t* xb   = (bf16_t*)(ws + SLOT);
        bf16_t* h1   = (bf16_t*)(ws + SLOT + SZ_XB);
        bf16_t* g    = (bf16_t*)(ws + SLOT + SZ_XB + SZ_H);

        convert_pad_x<<<M_ROWS, blk, 0, stream>>>(x, xb);
        transpose_convert<<<dim3(16, 4, 1), blk, 0, stream>>>(W1, slot, FEA, HD, 256, HD);
        gemm_tn<false, false><<<dim3(16, 13), blk, 0, stream>>>(xb, slot, b1, h0, M_ROWS, HD, 256);

        for (int l = 0; l < NL; l++) {
            transpose_convert<<<dim3(48, 16, 1), blk, 0, stream>>>(
                sruW + (size_t)l * HD * 3 * HD, slot, HD, 3*HD, HD, 3*HD);
            const bf16_t* hi = (l & 1) ? h1 : h0;
            bf16_t*       ho = (l & 1) ? h0 : h1;
            sru_layer<<<dim3(16, 10), blk, 0, stream>>>(
                hi, ho, slot,
                hidden + (size_t)l * NB * HD, srub + (size_t)l * 2 * HD,
                hid_out + (size_t)l * NB * HD);
        }
        transpose_convert<<<dim3(16, 16, 1), blk, 0, stream>>>(W3, slot, HD, HD, HD, HD);
        gemm_tn<false, true><<<dim3(16, 13), blk, 0, stream>>>(h0, slot, b3, g, M_ROWS, HD, HD);
        transpose_convert<<<dim3(18, 16, 1), blk, 0, stream>>>(W4, slot, HD, NOUT, HD, 1152);
        gemm_tn<true, false><<<dim3(18, 13), blk, 0, stream>>>(g, slot, b4, out, M_ROWS, NOUT, HD);
    }
}